// Round 11
// baseline (312.693 us; speedup 1.0000x reference)
//
#include <hip/hip_runtime.h>
#include <math.h>

// ---------------------------------------------------------------------------
// Problem constants
// ---------------------------------------------------------------------------
#define N_SEQ   896
#define DH      3072
#define NCTX    64
#define JLEN    127
#define DC      1024
#define HEADS   8
#define DHEAD   64
#define INNER   512   // HEADS*DHEAD
#define MKV     8128  // NCTX*JLEN
#define MKVPAD  8192

typedef __bf16 bf16x8 __attribute__((ext_vector_type(8)));
typedef float  f32x4  __attribute__((ext_vector_type(4)));

// workspace float offsets
#define OFF_EDOT   0LL
#define OFF_QBF    (OFF_EDOT + N_SEQ)
#define OFF_KBF    (OFF_QBF  + (long long)N_SEQ*INNER/2)     // bf16 896x512
#define OFF_VPM    (OFF_KBF  + (long long)NCTX*128*INNER/2)  // fp32 8128x8
#define OFF_VPNULL (OFF_VPM  + (long long)MKV*8)
#define OFF_WOP    (OFF_VPNULL + 8)                          // fp32 512 (wop vec)
#define OFF_BOP    (OFF_WOP  + INNER)
#define OFF_SBUF   (OFF_BOP  + 16)                           // fp32 64*8*896
#define OFF_ANQ    (OFF_SBUF + (long long)NCTX*HEADS*N_SEQ)  // bf16 896x3072
#define OFF_ANKV   (OFF_ANQ  + (long long)N_SEQ*DH/2)        // bf16 8192x1024
#define OFF_WQT    (OFF_ANKV + (long long)MKVPAD*DC/2)       // bf16 512x3072
#define OFF_WKT    (OFF_WQT  + (long long)INNER*DH/2)        // bf16 512x1024
#define OFF_WVPT   (OFF_WKT  + (long long)INNER*DC/2)        // bf16 16x1024
#define OFF_QSL    (OFF_WVPT + 16*1024/2)                    // fp32 8 x 896x512
#define OFF_CNT    (OFF_QSL  + (long long)8*N_SEQ*INNER)     // int cntQ[28], cntC[64]

// ---------------------------------------------------------------------------
__device__ __forceinline__ void async_copy16(const __bf16* g, __bf16* l) {
    __builtin_amdgcn_global_load_lds(
        (const __attribute__((address_space(1))) unsigned int*)g,
        (__attribute__((address_space(3))) unsigned int*)l,
        16, 0, 0);
}

// ---------------------------------------------------------------------------
// K0 prep_a: independent weight prep (no long serial tails) + counter zero:
//   blocks [0,512)      wop[j] = dot(Wo[j,:], Wp)  (one row per block)
//   block  512          BOP = dot(bo, Wp)
//   block  513          misc: WVPT zero pad + null_k rows of KBF + cnt zero
//   blocks [514,2562)   32x32 transposes: Wq->WQT (1536), Wkv k-half->WKT (512)
// ---------------------------------------------------------------------------
#define A_BOP  512
#define A_MISC 513
#define A_T0   514
#define GRIDA  (A_T0 + 2048)   // 2562

__global__ __launch_bounds__(256)
void prep_a_kernel(const float* __restrict__ Wq, const float* __restrict__ Wkv,
                   const float* __restrict__ Wo, const float* __restrict__ bo,
                   const float* __restrict__ Wp, const float* __restrict__ nullk,
                   __bf16* __restrict__ WQT, __bf16* __restrict__ WKT,
                   __bf16* __restrict__ WVPT, float* __restrict__ WOP,
                   float* __restrict__ BOP, __bf16* __restrict__ KBF,
                   int* __restrict__ CNT)
{
    __shared__ float tT[32][33];
    const int bid = blockIdx.x, tid = threadIdx.x;
    const int lane = tid & 63, wid = tid >> 6;

    if (bid < 512) {
        // ---- wop row: 256 threads x 12 floats, fully parallel ----
        const float* worow = Wo + (long long)bid * DH;
        float s = 0.f;
        #pragma unroll
        for (int c = 0; c < 3; ++c) {
            int col = c * 1024 + tid * 4;
            float4 a = *(const float4*)&worow[col];
            float4 w = *(const float4*)&Wp[col];
            s += a.x*w.x + a.y*w.y + a.z*w.z + a.w*w.w;
        }
        #pragma unroll
        for (int o = 1; o < 64; o <<= 1) s += __shfl_xor(s, o);
        float* red = &tT[0][0];
        if (lane == 0) red[wid] = s;
        __syncthreads();
        if (tid == 0) WOP[bid] = red[0] + red[1] + red[2] + red[3];
    } else if (bid == A_BOP) {
        // ---- BOP = dot(bo, Wp) ----
        float* red = &tT[0][0];
        float s = 0.f;
        #pragma unroll
        for (int i = 0; i < 3; ++i) {
            int k = i * 1024 + tid * 4;
            float4 a = *(const float4*)&bo[k];
            float4 w = *(const float4*)&Wp[k];
            s += a.x*w.x + a.y*w.y + a.z*w.z + a.w*w.w;
        }
        #pragma unroll
        for (int o = 1; o < 64; o <<= 1) s += __shfl_xor(s, o);
        if (lane == 0) red[wid] = s;
        __syncthreads();
        if (tid == 0) *BOP = red[0] + red[1] + red[2] + red[3];
    } else if (bid == A_MISC) {
        // ---- misc: WVPT zero pad + null_k rows of KBF + counters ----
        if (tid < 92) CNT[tid] = 0;
        for (int i = tid; i < 8 * 1024; i += 256)
            WVPT[8 * 1024 + i] = (__bf16)0.f;
        for (int i = tid; i < NCTX * INNER; i += 256) {
            int c = i >> 9, d2 = i & 511;
            KBF[(long long)(c * 128) * INNER + d2] = (__bf16)nullk[d2];
        }
    } else {
        // ---- 32x32 transpose tiles ----
        int t = bid - A_T0;
        const float* src; __bf16* dst; int srcS, dstS, rb, cb;
        if (t < 1536) {
            rb = (t >> 4) * 32; cb = (t & 15) * 32;
            src = Wq; srcS = INNER; dst = WQT; dstS = DH;
        } else {
            int bi = t - 1536;
            rb = (bi >> 4) * 32; cb = (bi & 15) * 32;
            src = Wkv; srcS = 2 * INNER; dst = WKT; dstS = DC;
        }
        int tx = tid & 31, ty = tid >> 5;
        #pragma unroll
        for (int i = 0; i < 32; i += 8)
            tT[ty + i][tx] = src[(long long)(rb + ty + i) * srcS + cb + tx];
        __syncthreads();
        #pragma unroll
        for (int i = 0; i < 32; i += 8)
            dst[(long long)(cb + ty + i) * dstS + rb + tx] = (__bf16)tT[tx][ty + i];
    }
}

// ---------------------------------------------------------------------------
// K1 prep_b: wop-dependent prep + LayerNorms (unchanged from round 10)
// ---------------------------------------------------------------------------
#define B_VPN  32
#define B_KV0  33
#define B_Q0   (B_KV0 + 2032)   // 2065
#define GRIDB  (B_Q0 + 224)     // 2289

__global__ __launch_bounds__(256)
void prep_b_kernel(const float* __restrict__ emb, const float* __restrict__ ctx,
                   const float* __restrict__ qg, const float* __restrict__ qb_,
                   const float* __restrict__ kvg, const float* __restrict__ kvb,
                   const float* __restrict__ Wp, const float* __restrict__ Wkv,
                   const float* __restrict__ nullv, const float* __restrict__ WOP,
                   __bf16* __restrict__ ANQ, __bf16* __restrict__ ANKV,
                   __bf16* __restrict__ WVPT, float* __restrict__ VPNULL,
                   float* __restrict__ EDOT)
{
    __shared__ float wsh[512];
    const int bid = blockIdx.x, tid = threadIdx.x;
    const int lane = tid & 63, wid = tid >> 6;

    if (bid < 32) {
        // ---- WVPT[h*1024+k] = dot(Wkv_v[k][h*64..+64], wop[h*64..+64]) ----
        wsh[tid] = WOP[tid];
        wsh[tid + 256] = WOP[tid + 256];
        __syncthreads();
        int t = bid * 256 + tid;          // 0..8191
        int k = t >> 3, h = t & 7;
        const float* src = Wkv + (long long)k * (2 * INNER) + INNER + h * 64;
        const float* wv = &wsh[h * 64];
        float s = 0.f;
        #pragma unroll
        for (int d2 = 0; d2 < 64; d2 += 4) {
            float4 a = *(const float4*)&src[d2];
            s += a.x*wv[d2] + a.y*wv[d2+1] + a.z*wv[d2+2] + a.w*wv[d2+3];
        }
        WVPT[h * 1024 + k] = (__bf16)s;
    } else if (bid == B_VPN) {
        // ---- VPNULL[h] = dot(null_v[h*64..], wop[h*64..]) ----
        wsh[tid] = WOP[tid];
        wsh[tid + 256] = WOP[tid + 256];
        __syncthreads();
        if (tid < 8) {
            int h = tid;
            float s = 0.f;
            #pragma unroll 16
            for (int d = 0; d < 64; ++d) s += nullv[h * 64 + d] * wsh[h * 64 + d];
            VPNULL[h] = s;
        }
    } else if (bid < B_Q0) {
        // ---- kv LN: one wave per row; nt loads (ctx read exactly once) ----
        int r = (bid - B_KV0) * 4 + wid;             // 0..8127
        const float* x = ctx + (long long)r * DC;
        f32x4 xv[4];
        float s = 0.f, ss = 0.f;
        #pragma unroll
        for (int c = 0; c < 4; ++c) {
            const f32x4* p = (const f32x4*)&x[c * 256 + lane * 4];
            xv[c] = __builtin_nontemporal_load(p);
            s  += xv[c][0] + xv[c][1] + xv[c][2] + xv[c][3];
            ss += xv[c][0]*xv[c][0] + xv[c][1]*xv[c][1]
                + xv[c][2]*xv[c][2] + xv[c][3]*xv[c][3];
        }
        #pragma unroll
        for (int o = 1; o < 64; o <<= 1) { s += __shfl_xor(s, o); ss += __shfl_xor(ss, o); }
        float m  = s * (1.f / DC);
        float rs = rsqrtf(ss * (1.f / DC) - m * m + 1e-5f);
        __bf16* op = ANKV + (long long)r * DC;
        #pragma unroll
        for (int c = 0; c < 4; ++c) {
            int col = c * 256 + lane * 4;
            float4 g4 = *(const float4*)&kvg[col];
            float4 b4 = *(const float4*)&kvb[col];
            __bf16 ov[4];
            ov[0] = (__bf16)((xv[c][0] - m) * rs * g4.x + b4.x);
            ov[1] = (__bf16)((xv[c][1] - m) * rs * g4.y + b4.y);
            ov[2] = (__bf16)((xv[c][2] - m) * rs * g4.z + b4.z);
            ov[3] = (__bf16)((xv[c][3] - m) * rs * g4.w + b4.w);
            *(ushort4*)&op[col] = *(ushort4*)ov;
        }
    } else {
        // ---- q LN: one wave per row, two-pass (emb re-read from L2) ----
        int r = (bid - B_Q0) * 4 + wid;              // 0..895
        const float* x = emb + (long long)r * DH;
        float s = 0.f, ss = 0.f, dp = 0.f;
        #pragma unroll
        for (int c = 0; c < 12; ++c) {
            int col = c * 256 + lane * 4;
            float4 a = *(const float4*)&x[col];
            float4 w = *(const float4*)&Wp[col];
            s  += a.x + a.y + a.z + a.w;
            ss += a.x*a.x + a.y*a.y + a.z*a.z + a.w*a.w;
            dp += a.x*w.x + a.y*w.y + a.z*w.z + a.w*w.w;
        }
        #pragma unroll
        for (int o = 1; o < 64; o <<= 1) {
            s += __shfl_xor(s, o); ss += __shfl_xor(ss, o); dp += __shfl_xor(dp, o);
        }
        float m  = s * (1.f / DH);
        float rs = rsqrtf(ss * (1.f / DH) - m * m + 1e-5f);
        __bf16* op = ANQ + (long long)r * DH;
        #pragma unroll
        for (int c = 0; c < 12; ++c) {
            int col = c * 256 + lane * 4;
            float4 a  = *(const float4*)&x[col];
            float4 g4 = *(const float4*)&qg[col];
            float4 b4 = *(const float4*)&qb_[col];
            __bf16 ov[4];
            ov[0] = (__bf16)((a.x - m) * rs * g4.x + b4.x);
            ov[1] = (__bf16)((a.y - m) * rs * g4.y + b4.y);
            ov[2] = (__bf16)((a.z - m) * rs * g4.z + b4.z);
            ov[3] = (__bf16)((a.w - m) * rs * g4.w + b4.w);
            *(ushort4*)&op[col] = *(ushort4*)ov;
        }
        if (lane == 0) EDOT[r] = dp;
    }
}

// ---------------------------------------------------------------------------
// K2: merged projection GEMM + INLINE split-K reduce (last-block pattern).
// blocks [0,224):   q split-K=8 -> fp32 slice; 8th finisher per region
//                   reduces 128x128 to bf16 QBF (same slice order as the old
//                   qreduce -> bit-identical).
// blocks [224,480): k GEMM -> bf16 KBF scatter (+vp on n0==0)
// ---------------------------------------------------------------------------
__global__ __launch_bounds__(256)
void proj_kernel(const __bf16* __restrict__ ANQ, const __bf16* __restrict__ WQT,
                 const __bf16* __restrict__ ANKV, const __bf16* __restrict__ WKT,
                 const __bf16* __restrict__ WVPT,
                 float* __restrict__ qsl, __bf16* __restrict__ kout,
                 float* __restrict__ vpm, __bf16* __restrict__ qbf,
                 int* __restrict__ cntQ) {
    __shared__ __align__(16) __bf16 As[128 * 32];
    __shared__ __align__(16) __bf16 Bs[128 * 32];
    __shared__ int sOld;
    int b = blockIdx.x;
    int tid = threadIdx.x;
    int lane = tid & 63, w = tid >> 6;
    int n16 = lane & 15, quad = lane >> 4;
    int wr = (w >> 1) * 64, wc = (w & 1) * 64;

    const __bf16 *A, *B;
    int K, kbeg, kend, mode, slice = 0, rem = 0;
    long long m0, n0;
    if (b < 224) {
        mode = 0; slice = b / 28;
        rem = b % 28;
        m0 = (long long)(rem % 7) * 128;
        n0 = (long long)(rem / 7) * 128;
        K = DH; kbeg = slice * 384; kend = kbeg + 384;
        A = ANQ; B = WQT;
    } else {
        mode = 1;
        int b2 = b - 224;
        m0 = (long long)(b2 & 63) * 128;
        n0 = (long long)(b2 >> 6) * 128;
        K = DC; kbeg = 0; kend = DC;
        A = ANKV; B = WKT;
    }
    bool dovp = (mode == 1) && (n0 == 0);

    const __bf16* aG = A + (m0 + (tid >> 2)) * K + (tid & 3) * 8;
    const __bf16* bG = B + (n0 + (tid >> 2)) * K + (tid & 3) * 8;
    __bf16* aL = As + tid * 8;
    __bf16* bL = Bs + tid * 8;

    f32x4 acc[4][4], accv[4];
    const f32x4 z = {0.f, 0.f, 0.f, 0.f};
    #pragma unroll
    for (int i = 0; i < 4; ++i) {
        accv[i] = z;
        #pragma unroll
        for (int j = 0; j < 4; ++j) acc[i][j] = z;
    }

    for (int k0 = kbeg; k0 < kend; k0 += 32) {
        async_copy16(aG + k0, aL);
        async_copy16(aG + (long long)64 * K + k0, aL + 2048);
        async_copy16(bG + k0, bL);
        async_copy16(bG + (long long)64 * K + k0, bL + 2048);
        bf16x8 bv;
        if (dovp) bv = *(const bf16x8*)&WVPT[n16 * 1024 + k0 + quad * 8];
        __syncthreads();
        bf16x8 af[4], bfr[4];
        #pragma unroll
        for (int i = 0; i < 4; ++i)
            af[i]  = *(const bf16x8*)&As[(wr + i * 16 + n16) * 32 + quad * 8];
        #pragma unroll
        for (int j = 0; j < 4; ++j)
            bfr[j] = *(const bf16x8*)&Bs[(wc + j * 16 + n16) * 32 + quad * 8];
        #pragma unroll
        for (int i = 0; i < 4; ++i)
            #pragma unroll
            for (int j = 0; j < 4; ++j)
                acc[i][j] = __builtin_amdgcn_mfma_f32_16x16x32_bf16(af[i], bfr[j], acc[i][j], 0, 0, 0);
        if (dovp) {
            #pragma unroll
            for (int i = 0; i < 4; ++i)
                accv[i] = __builtin_amdgcn_mfma_f32_16x16x32_bf16(af[i], bv, accv[i], 0, 0, 0);
        }
        __syncthreads();
    }

    if (mode == 0) {
        float* qdst = qsl + (long long)slice * (N_SEQ * INNER);
        #pragma unroll
        for (int i = 0; i < 4; ++i)
            #pragma unroll
            for (int r = 0; r < 4; ++r) {
                long long gr = m0 + wr + i * 16 + quad * 4 + r;
                #pragma unroll
                for (int j = 0; j < 4; ++j) {
                    long long gc = n0 + wc + j * 16 + n16;
                    qdst[gr * INNER + gc] = acc[i][j][r];
                }
            }
        // last-block-per-region reduce (release/acquire via threadfence)
        __threadfence();
        if (tid == 0) sOld = atomicAdd(&cntQ[rem], 1);
        __syncthreads();
        if (sOld == 7) {
            __threadfence();
            for (int idx = tid; idx < 128 * 32; idx += 256) {
                long long gr = m0 + (idx >> 5);
                long long gc = n0 + (idx & 31) * 4;
                float4 s4 = {0.f, 0.f, 0.f, 0.f};
                #pragma unroll
                for (int k = 0; k < 8; ++k) {
                    float4 a = *(const float4*)&qsl[(long long)k * (N_SEQ * INNER) + gr * INNER + gc];
                    s4.x += a.x; s4.y += a.y; s4.z += a.z; s4.w += a.w;
                }
                __bf16 ov[4] = {(__bf16)s4.x, (__bf16)s4.y, (__bf16)s4.z, (__bf16)s4.w};
                *(ushort4*)&qbf[gr * INNER + gc] = *(ushort4*)ov;
            }
        }
    } else {
        #pragma unroll
        for (int i = 0; i < 4; ++i)
            #pragma unroll
            for (int r = 0; r < 4; ++r) {
                long long gr = m0 + wr + i * 16 + quad * 4 + r;
                if (gr >= MKV) continue;
                int cc = (int)(gr / JLEN), jj = (int)(gr % JLEN);
                #pragma unroll
                for (int j = 0; j < 4; ++j) {
                    long long gc = n0 + wc + j * 16 + n16;
                    kout[((long long)(cc * 128) + jj + 1) * INNER + gc] = (__bf16)acc[i][j][r];
                }
                if (dovp && n16 < 8) vpm[gr * 8 + n16] = accv[i][r];
            }
    }
}

// ---------------------------------------------------------------------------
// K3: attention via MFMA + INLINE final (last-block-per-c pattern).
// 512 blocks (one per (c,h)); K staged once, loop 7 q-positions; the 8th
// finisher per c computes softplus(edot + sum_h SBUF + bop + bp) -> out.
// ---------------------------------------------------------------------------
#define KROW 72   // LDS row stride in bf16 (64 data + 8 pad)

__global__ __launch_bounds__(256)
void attn_mfma_kernel(const __bf16* __restrict__ qb, const __bf16* __restrict__ kb,
                      const float* __restrict__ vpm, const float* __restrict__ vpnull,
                      const int* __restrict__ mask, float* __restrict__ s_buf,
                      const float* __restrict__ e_dot, const float* __restrict__ bop,
                      const float* __restrict__ bp, float* __restrict__ out,
                      int* __restrict__ cntC) {
    __shared__ __align__(16) __bf16 ksh[128 * KROW];
    __shared__ float vpsh[128];
    __shared__ float amsh[128];
    __shared__ int sOld;
    int ch = blockIdx.x;
    int h = ch & 7, c = ch >> 3;
    int tid = threadIdx.x;
    int lane = tid & 63, w = tid >> 6;
    int n16 = lane & 15, quad = lane >> 4;

    const __bf16* kbase = kb + (long long)(c * 128) * INNER + h * DHEAD;
    #pragma unroll
    for (int p = 0; p < 4; ++p) {
        int chunk = tid + p * 256;          // 0..1023
        int row = chunk >> 3, o = chunk & 7;
        bf16x8 v = *(const bf16x8*)(kbase + (long long)row * INNER + o * 8);
        *(bf16x8*)&ksh[row * KROW + o * 8] = v;
    }
    if (tid < 128) {
        vpsh[tid] = (tid == 0) ? vpnull[h] : vpm[(long long)(c * JLEN + tid - 1) * 8 + h];
        amsh[tid] = (tid == 0) ? 0.f : (mask[tid - 1] ? 0.f : -3.0e38f);
    }
    __syncthreads();

    bf16x8 bF[8][2];
    #pragma unroll
    for (int t = 0; t < 8; ++t)
        #pragma unroll
        for (int s = 0; s < 2; ++s)
            bF[t][s] = *(const bf16x8*)&ksh[(t * 16 + n16) * KROW + s * 32 + quad * 8];

    float vpv[8], am[8];
    #pragma unroll
    for (int t = 0; t < 8; ++t) {
        vpv[t] = vpsh[t * 16 + n16];
        am[t]  = amsh[t * 16 + n16];
    }

    const __bf16* qbase = qb + h * DHEAD;
    const f32x4 zero = {0.f, 0.f, 0.f, 0.f};

    for (int xi = 0; xi < 7; ++xi) {
        bf16x8 aF[2][2];
        int r0s[2];
        #pragma unroll
        for (int it2 = 0; it2 < 2; ++it2) {
            int tile = xi * 8 + it2 * 4 + w;   // 0..55
            r0s[it2] = tile * 16;
            const __bf16* qrow = qbase + (long long)(r0s[it2] + n16) * INNER + quad * 8;
            aF[it2][0] = *(const bf16x8*)(qrow);
            aF[it2][1] = *(const bf16x8*)(qrow + 32);
        }

        #pragma unroll
        for (int it2 = 0; it2 < 2; ++it2) {
            int r0 = r0s[it2];
            f32x4 acc[8];
            #pragma unroll
            for (int t = 0; t < 8; ++t) {
                acc[t] = __builtin_amdgcn_mfma_f32_16x16x32_bf16(aF[it2][0], bF[t][0], zero,   0, 0, 0);
                acc[t] = __builtin_amdgcn_mfma_f32_16x16x32_bf16(aF[it2][1], bF[t][1], acc[t], 0, 0, 0);
            }
            float mloc = -3.0e38f;
            #pragma unroll
            for (int t = 0; t < 8; ++t)
                #pragma unroll
                for (int r = 0; r < 4; ++r)
                    mloc = fmaxf(mloc, acc[t][r] * 0.125f + am[t]);
            #pragma unroll
            for (int o = 1; o < 16; o <<= 1) mloc = fmaxf(mloc, __shfl_xor(mloc, o, 16));
            float lr[4] = {0.f, 0.f, 0.f, 0.f}, pr[4] = {0.f, 0.f, 0.f, 0.f};
            #pragma unroll
            for (int t = 0; t < 8; ++t) {
                #pragma unroll
                for (int r = 0; r < 4; ++r) {
                    float e = __expf(acc[t][r] * 0.125f + am[t] - mloc);
                    lr[r] += e; pr[r] += e * vpv[t];
                }
            }
            #pragma unroll
            for (int o = 1; o < 16; o <<= 1) {
                #pragma unroll
                for (int r = 0; r < 4; ++r) {
                    lr[r] += __shfl_xor(lr[r], o, 16);
                    pr[r] += __shfl_xor(pr[r], o, 16);
                }
            }
            if (n16 == 0) {
                #pragma unroll
                for (int r = 0; r < 4; ++r)
                    s_buf[(long long)ch * N_SEQ + r0 + quad * 4 + r] = pr[r] / lr[r];
            }
        }
    }

    // last-block-per-c: fuse the final softplus (saves a dispatch boundary)
    __threadfence();
    if (tid == 0) sOld = atomicAdd(&cntC[c], 1);
    __syncthreads();
    if (sOld == 7) {
        __threadfence();
        float bsum = *bop + *bp;
        for (int n = tid; n < N_SEQ; n += 256) {
            float s = 0.f;
            #pragma unroll
            for (int hh = 0; hh < 8; ++hh)
                s += s_buf[((long long)(c * HEADS + hh)) * N_SEQ + n];
            float x = e_dot[n] + s + bsum;
            out[n * NCTX + c] = fmaxf(x, 0.f) + log1pf(__expf(-fabsf(x)));
        }
    }
}

// ---------------------------------------------------------------------------
extern "C" void kernel_launch(void* const* d_in, const int* in_sizes, int n_in,
                              void* d_out, int out_size, void* d_ws, size_t ws_size,
                              hipStream_t stream) {
    const float* emb   = (const float*)d_in[0];
    const float* ctx   = (const float*)d_in[1];
    const int*   cmask = (const int*)  d_in[2];
    const float* qg    = (const float*)d_in[3];
    const float* qb_   = (const float*)d_in[4];
    const float* kvg   = (const float*)d_in[5];
    const float* kvb   = (const float*)d_in[6];
    const float* Wq    = (const float*)d_in[7];
    const float* Wkv   = (const float*)d_in[8];
    const float* nullk = (const float*)d_in[9];
    const float* nullv = (const float*)d_in[10];
    const float* Wo    = (const float*)d_in[11];
    const float* bo    = (const float*)d_in[12];
    const float* Wp    = (const float*)d_in[13];
    const float* bp    = (const float*)d_in[14];
    float* out  = (float*)d_out;
    float* ws_f = (float*)d_ws;

    float*  EDOT   = ws_f + OFF_EDOT;
    __bf16* QBF    = (__bf16*)(ws_f + OFF_QBF);
    __bf16* KBF    = (__bf16*)(ws_f + OFF_KBF);
    float*  VPM    = ws_f + OFF_VPM;
    float*  VPNULL = ws_f + OFF_VPNULL;
    float*  WOP    = ws_f + OFF_WOP;
    float*  BOP    = ws_f + OFF_BOP;
    float*  SBUF   = ws_f + OFF_SBUF;
    __bf16* ANQ    = (__bf16*)(ws_f + OFF_ANQ);
    __bf16* ANKV   = (__bf16*)(ws_f + OFF_ANKV);
    __bf16* WQT    = (__bf16*)(ws_f + OFF_WQT);
    __bf16* WKT    = (__bf16*)(ws_f + OFF_WKT);
    __bf16* WVPT   = (__bf16*)(ws_f + OFF_WVPT);
    float*  QSL    = ws_f + OFF_QSL;
    int*    CNT    = (int*)(ws_f + OFF_CNT);

    prep_a_kernel<<<GRIDA, 256, 0, stream>>>(
        Wq, Wkv, Wo, bo, Wp, nullk, WQT, WKT, WVPT, WOP, BOP, KBF, CNT);
    prep_b_kernel<<<GRIDB, 256, 0, stream>>>(
        emb, ctx, qg, qb_, kvg, kvb, Wp, Wkv, nullv, WOP,
        ANQ, ANKV, WVPT, VPNULL, EDOT);
    proj_kernel<<<480, 256, 0, stream>>>(
        ANQ, WQT, ANKV, WKT, WVPT, QSL, KBF, VPM, QBF, CNT);
    attn_mfma_kernel<<<NCTX * HEADS, 256, 0, stream>>>(
        QBF, KBF, VPM, VPNULL, cmask, SBUF, EDOT, BOP, bp, out, CNT + 28);
}

// Round 12
// 211.692 us; speedup vs baseline: 1.4771x; 1.4771x over previous
//
#include <hip/hip_runtime.h>
#include <math.h>

// ---------------------------------------------------------------------------
// Problem constants
// ---------------------------------------------------------------------------
#define N_SEQ   896
#define DH      3072
#define NCTX    64
#define JLEN    127
#define DC      1024
#define HEADS   8
#define DHEAD   64
#define INNER   512   // HEADS*DHEAD
#define MKV     8128  // NCTX*JLEN
#define MKVPAD  8192

typedef __bf16 bf16x8 __attribute__((ext_vector_type(8)));
typedef float  f32x4  __attribute__((ext_vector_type(4)));

// workspace float offsets
#define OFF_EDOT   0LL
#define OFF_QBF    (OFF_EDOT + N_SEQ)
#define OFF_KBF    (OFF_QBF  + (long long)N_SEQ*INNER/2)     // bf16 896x512
#define OFF_VPM    (OFF_KBF  + (long long)NCTX*128*INNER/2)  // fp32 8128x8
#define OFF_VPNULL (OFF_VPM  + (long long)MKV*8)
#define OFF_WOP    (OFF_VPNULL + 8)                          // (unused, layout kept)
#define OFF_BOP    (OFF_WOP  + INNER)
#define OFF_SBUF   (OFF_BOP  + 16)                           // fp32 64*8*896
#define OFF_ANQ    (OFF_SBUF + (long long)NCTX*HEADS*N_SEQ)  // bf16 896x3072
#define OFF_ANKV   (OFF_ANQ  + (long long)N_SEQ*DH/2)        // bf16 8192x1024
#define OFF_WQT    (OFF_ANKV + (long long)MKVPAD*DC/2)       // bf16 512x3072
#define OFF_WKT    (OFF_WQT  + (long long)INNER*DH/2)        // bf16 512x1024
#define OFF_WVPT   (OFF_WKT  + (long long)INNER*DC/2)        // bf16 16x1024
#define OFF_QSL    (OFF_WVPT + 16*1024/2)                    // fp32 8 x 896x512

// ---------------------------------------------------------------------------
__device__ __forceinline__ void async_copy16(const __bf16* g, __bf16* l) {
    __builtin_amdgcn_global_load_lds(
        (const __attribute__((address_space(1))) unsigned int*)g,
        (__attribute__((address_space(3))) unsigned int*)l,
        16, 0, 0);
}

// ---------------------------------------------------------------------------
// K1 prep: ALL prep in one kernel (no internal dependencies, no fences).
// Per-head blocks compute their OWN wop slice (Wp in LDS, wave-per-row) so
// the old prep_a->prep_b boundary disappears.
//   blocks [0,8)        per-head: wop slice -> WVPT row + VPNULL
//   block  8            BOP = dot(bo, Wp)
//   block  9            misc: WVPT zero pad + null_k rows of KBF
//   blocks [10,2042)    kv LayerNorm, wave-per-row, nt loads (ctx read-once)
//   blocks [2042,2266)  q LayerNorm + emb.Wp dot, wave-per-row, two-pass
//   blocks [2266,4314)  32x32 transposes: Wq->WQT (1536), Wkv k-half->WKT (512)
// ---------------------------------------------------------------------------
#define P_KV0  10
#define P_Q0   (P_KV0 + 2032)   // 2042
#define P_T0   (P_Q0 + 224)     // 2266
#define GRIDP  (P_T0 + 2048)    // 4314

__global__ __launch_bounds__(256)
void prep_kernel(const float* __restrict__ emb, const float* __restrict__ ctx,
                 const float* __restrict__ qg, const float* __restrict__ qb_,
                 const float* __restrict__ kvg, const float* __restrict__ kvb,
                 const float* __restrict__ Wq, const float* __restrict__ Wkv,
                 const float* __restrict__ Wo, const float* __restrict__ bo,
                 const float* __restrict__ Wp,
                 const float* __restrict__ nullk, const float* __restrict__ nullv,
                 __bf16* __restrict__ ANQ, __bf16* __restrict__ ANKV,
                 __bf16* __restrict__ WQT, __bf16* __restrict__ WKT,
                 __bf16* __restrict__ WVPT, float* __restrict__ VPNULL,
                 float* __restrict__ EDOT, float* __restrict__ BOP,
                 __bf16* __restrict__ KBF)
{
    __shared__ __align__(16) float SM[3072 + 64];   // Wp stage + wop slice / tT alias
    const int bid = blockIdx.x, tid = threadIdx.x;
    const int lane = tid & 63, wid = tid >> 6;

    if (bid < 8) {
        // ---- per-head: self-contained wop slice -> WVPT row + VPNULL ----
        int h = bid;
        float* wpsh = SM;              // 3072 floats
        float* wops = SM + 3072;       // 64 floats
        // stage Wp into LDS (768 float4)
        for (int i = tid; i < 768; i += 256)
            ((f32x4*)wpsh)[i] = ((const f32x4*)Wp)[i];
        __syncthreads();
        // wop slice: each wave 16 rows; per row 12 indep float4 + lane reduce
        for (int rr = 0; rr < 16; ++rr) {
            int d = wid * 16 + rr;
            const float* worow = Wo + (long long)(h * 64 + d) * DH;
            float s = 0.f;
            #pragma unroll
            for (int c = 0; c < 12; ++c) {
                int col = c * 256 + lane * 4;
                float4 a = *(const float4*)&worow[col];
                s += a.x*wpsh[col] + a.y*wpsh[col+1] + a.z*wpsh[col+2] + a.w*wpsh[col+3];
            }
            #pragma unroll
            for (int o = 1; o < 64; o <<= 1) s += __shfl_xor(s, o);
            if (lane == 0) wops[d] = s;
        }
        __syncthreads();
        if (tid < 64) {
            float v = nullv[h * 64 + tid] * wops[tid];
            #pragma unroll
            for (int o = 1; o < 64; o <<= 1) v += __shfl_xor(v, o);
            if (tid == 0) VPNULL[h] = v;
        }
        #pragma unroll
        for (int kk = 0; kk < 4; ++kk) {
            int k = kk * 256 + tid;
            const float* src = Wkv + (long long)k * (2 * INNER) + INNER + h * 64;
            float s2 = 0.f;
            #pragma unroll
            for (int d2 = 0; d2 < 64; d2 += 4) {
                float4 a = *(const float4*)&src[d2];
                s2 += a.x*wops[d2] + a.y*wops[d2+1] + a.z*wops[d2+2] + a.w*wops[d2+3];
            }
            WVPT[h * 1024 + k] = (__bf16)s2;
        }
    } else if (bid == 8) {
        // ---- BOP = dot(bo, Wp) ----
        float* red = SM;
        float s = 0.f;
        #pragma unroll
        for (int i = 0; i < 3; ++i) {
            int k = i * 1024 + tid * 4;
            float4 a = *(const float4*)&bo[k];
            float4 w = *(const float4*)&Wp[k];
            s += a.x*w.x + a.y*w.y + a.z*w.z + a.w*w.w;
        }
        #pragma unroll
        for (int o = 1; o < 64; o <<= 1) s += __shfl_xor(s, o);
        if (lane == 0) red[wid] = s;
        __syncthreads();
        if (tid == 0) *BOP = red[0] + red[1] + red[2] + red[3];
    } else if (bid == 9) {
        // ---- misc: WVPT zero pad rows 8..15 + null_k rows of KBF ----
        for (int i = tid; i < 8 * 1024; i += 256)
            WVPT[8 * 1024 + i] = (__bf16)0.f;
        for (int i = tid; i < NCTX * INNER; i += 256) {
            int c = i >> 9, d2 = i & 511;
            KBF[(long long)(c * 128) * INNER + d2] = (__bf16)nullk[d2];
        }
    } else if (bid < P_Q0) {
        // ---- kv LN: one wave per row; nt loads (ctx read exactly once) ----
        int r = (bid - P_KV0) * 4 + wid;             // 0..8127
        const float* x = ctx + (long long)r * DC;
        f32x4 xv[4];
        float s = 0.f, ss = 0.f;
        #pragma unroll
        for (int c = 0; c < 4; ++c) {
            const f32x4* p = (const f32x4*)&x[c * 256 + lane * 4];
            xv[c] = __builtin_nontemporal_load(p);
            s  += xv[c][0] + xv[c][1] + xv[c][2] + xv[c][3];
            ss += xv[c][0]*xv[c][0] + xv[c][1]*xv[c][1]
                + xv[c][2]*xv[c][2] + xv[c][3]*xv[c][3];
        }
        #pragma unroll
        for (int o = 1; o < 64; o <<= 1) { s += __shfl_xor(s, o); ss += __shfl_xor(ss, o); }
        float m  = s * (1.f / DC);
        float rs = rsqrtf(ss * (1.f / DC) - m * m + 1e-5f);
        __bf16* op = ANKV + (long long)r * DC;
        #pragma unroll
        for (int c = 0; c < 4; ++c) {
            int col = c * 256 + lane * 4;
            float4 g4 = *(const float4*)&kvg[col];
            float4 b4 = *(const float4*)&kvb[col];
            __bf16 ov[4];
            ov[0] = (__bf16)((xv[c][0] - m) * rs * g4.x + b4.x);
            ov[1] = (__bf16)((xv[c][1] - m) * rs * g4.y + b4.y);
            ov[2] = (__bf16)((xv[c][2] - m) * rs * g4.z + b4.z);
            ov[3] = (__bf16)((xv[c][3] - m) * rs * g4.w + b4.w);
            *(ushort4*)&op[col] = *(ushort4*)ov;
        }
    } else if (bid < P_T0) {
        // ---- q LN: one wave per row, two-pass (emb re-read from L2) ----
        int r = (bid - P_Q0) * 4 + wid;              // 0..895
        const float* x = emb + (long long)r * DH;
        float s = 0.f, ss = 0.f, dp = 0.f;
        #pragma unroll
        for (int c = 0; c < 12; ++c) {
            int col = c * 256 + lane * 4;
            float4 a = *(const float4*)&x[col];
            float4 w = *(const float4*)&Wp[col];
            s  += a.x + a.y + a.z + a.w;
            ss += a.x*a.x + a.y*a.y + a.z*a.z + a.w*a.w;
            dp += a.x*w.x + a.y*w.y + a.z*w.z + a.w*w.w;
        }
        #pragma unroll
        for (int o = 1; o < 64; o <<= 1) {
            s += __shfl_xor(s, o); ss += __shfl_xor(ss, o); dp += __shfl_xor(dp, o);
        }
        float m  = s * (1.f / DH);
        float rs = rsqrtf(ss * (1.f / DH) - m * m + 1e-5f);
        __bf16* op = ANQ + (long long)r * DH;
        #pragma unroll
        for (int c = 0; c < 12; ++c) {
            int col = c * 256 + lane * 4;
            float4 a  = *(const float4*)&x[col];
            float4 g4 = *(const float4*)&qg[col];
            float4 b4 = *(const float4*)&qb_[col];
            __bf16 ov[4];
            ov[0] = (__bf16)((a.x - m) * rs * g4.x + b4.x);
            ov[1] = (__bf16)((a.y - m) * rs * g4.y + b4.y);
            ov[2] = (__bf16)((a.z - m) * rs * g4.z + b4.z);
            ov[3] = (__bf16)((a.w - m) * rs * g4.w + b4.w);
            *(ushort4*)&op[col] = *(ushort4*)ov;
        }
        if (lane == 0) EDOT[r] = dp;
    } else {
        // ---- 32x32 transpose tiles ----
        int t = bid - P_T0;
        float (*tT)[33] = (float(*)[33])SM;
        const float* src; __bf16* dst; int srcS, dstS, rb, cb;
        if (t < 1536) {
            rb = (t >> 4) * 32; cb = (t & 15) * 32;
            src = Wq; srcS = INNER; dst = WQT; dstS = DH;
        } else {
            int bi = t - 1536;
            rb = (bi >> 4) * 32; cb = (bi & 15) * 32;
            src = Wkv; srcS = 2 * INNER; dst = WKT; dstS = DC;
        }
        int tx = tid & 31, ty = tid >> 5;
        #pragma unroll
        for (int i = 0; i < 32; i += 8)
            tT[ty + i][tx] = src[(long long)(rb + ty + i) * srcS + cb + tx];
        __syncthreads();
        #pragma unroll
        for (int i = 0; i < 32; i += 8)
            dst[(long long)(cb + ty + i) * dstS + rb + tx] = (__bf16)tT[tx][ty + i];
    }
}

// ---------------------------------------------------------------------------
// K2: merged projection GEMM (bf16 MFMA, 128x128 tile, BK=32, single-buffer,
// global_load_lds). 480 blocks; plain stores, NO fences/atomics.
// ---------------------------------------------------------------------------
__global__ __launch_bounds__(256)
void proj_kernel(const __bf16* __restrict__ ANQ, const __bf16* __restrict__ WQT,
                 const __bf16* __restrict__ ANKV, const __bf16* __restrict__ WKT,
                 const __bf16* __restrict__ WVPT,
                 float* __restrict__ qsl, __bf16* __restrict__ kout,
                 float* __restrict__ vpm) {
    __shared__ __align__(16) __bf16 As[128 * 32];
    __shared__ __align__(16) __bf16 Bs[128 * 32];
    int b = blockIdx.x;
    int tid = threadIdx.x;
    int lane = tid & 63, w = tid >> 6;
    int n16 = lane & 15, quad = lane >> 4;
    int wr = (w >> 1) * 64, wc = (w & 1) * 64;

    const __bf16 *A, *B;
    int K, kbeg, kend, mode, slice = 0;
    long long m0, n0;
    if (b < 224) {
        mode = 0; slice = b / 28;
        int rem = b % 28;
        m0 = (long long)(rem % 7) * 128;
        n0 = (long long)(rem / 7) * 128;
        K = DH; kbeg = slice * 384; kend = kbeg + 384;
        A = ANQ; B = WQT;
    } else {
        mode = 1;
        int b2 = b - 224;
        m0 = (long long)(b2 & 63) * 128;
        n0 = (long long)(b2 >> 6) * 128;
        K = DC; kbeg = 0; kend = DC;
        A = ANKV; B = WKT;
    }
    bool dovp = (mode == 1) && (n0 == 0);

    const __bf16* aG = A + (m0 + (tid >> 2)) * K + (tid & 3) * 8;
    const __bf16* bG = B + (n0 + (tid >> 2)) * K + (tid & 3) * 8;
    __bf16* aL = As + tid * 8;
    __bf16* bL = Bs + tid * 8;

    f32x4 acc[4][4], accv[4];
    const f32x4 z = {0.f, 0.f, 0.f, 0.f};
    #pragma unroll
    for (int i = 0; i < 4; ++i) {
        accv[i] = z;
        #pragma unroll
        for (int j = 0; j < 4; ++j) acc[i][j] = z;
    }

    for (int k0 = kbeg; k0 < kend; k0 += 32) {
        async_copy16(aG + k0, aL);
        async_copy16(aG + (long long)64 * K + k0, aL + 2048);
        async_copy16(bG + k0, bL);
        async_copy16(bG + (long long)64 * K + k0, bL + 2048);
        bf16x8 bv;
        if (dovp) bv = *(const bf16x8*)&WVPT[n16 * 1024 + k0 + quad * 8];
        __syncthreads();
        bf16x8 af[4], bfr[4];
        #pragma unroll
        for (int i = 0; i < 4; ++i)
            af[i]  = *(const bf16x8*)&As[(wr + i * 16 + n16) * 32 + quad * 8];
        #pragma unroll
        for (int j = 0; j < 4; ++j)
            bfr[j] = *(const bf16x8*)&Bs[(wc + j * 16 + n16) * 32 + quad * 8];
        #pragma unroll
        for (int i = 0; i < 4; ++i)
            #pragma unroll
            for (int j = 0; j < 4; ++j)
                acc[i][j] = __builtin_amdgcn_mfma_f32_16x16x32_bf16(af[i], bfr[j], acc[i][j], 0, 0, 0);
        if (dovp) {
            #pragma unroll
            for (int i = 0; i < 4; ++i)
                accv[i] = __builtin_amdgcn_mfma_f32_16x16x32_bf16(af[i], bv, accv[i], 0, 0, 0);
        }
        __syncthreads();
    }

    if (mode == 0) {
        float* qdst = qsl + (long long)slice * (N_SEQ * INNER);
        #pragma unroll
        for (int i = 0; i < 4; ++i)
            #pragma unroll
            for (int r = 0; r < 4; ++r) {
                long long gr = m0 + wr + i * 16 + quad * 4 + r;
                #pragma unroll
                for (int j = 0; j < 4; ++j) {
                    long long gc = n0 + wc + j * 16 + n16;
                    qdst[gr * INNER + gc] = acc[i][j][r];
                }
            }
    } else {
        #pragma unroll
        for (int i = 0; i < 4; ++i)
            #pragma unroll
            for (int r = 0; r < 4; ++r) {
                long long gr = m0 + wr + i * 16 + quad * 4 + r;
                if (gr >= MKV) continue;
                int cc = (int)(gr / JLEN), jj = (int)(gr % JLEN);
                #pragma unroll
                for (int j = 0; j < 4; ++j) {
                    long long gc = n0 + wc + j * 16 + n16;
                    kout[((long long)(cc * 128) + jj + 1) * INNER + gc] = (__bf16)acc[i][j][r];
                }
                if (dovp && n16 < 8) vpm[gr * 8 + n16] = accv[i][r];
            }
    }
}

// ---------------------------------------------------------------------------
// K3: reduce 8 q split-K slices -> bf16 (float4-vectorized, 448 blocks)
// ---------------------------------------------------------------------------
__global__ __launch_bounds__(256)
void qreduce_kernel(const float* __restrict__ qsl, __bf16* __restrict__ qbf) {
    int i = blockIdx.x * 256 + threadIdx.x;   // 0..114687 float4 groups
    float4 s4 = {0.f, 0.f, 0.f, 0.f};
    #pragma unroll
    for (int k = 0; k < 8; ++k) {
        float4 a = *(const float4*)&qsl[(long long)k * (N_SEQ * INNER) + i * 4];
        s4.x += a.x; s4.y += a.y; s4.z += a.z; s4.w += a.w;
    }
    __bf16 ov[4] = {(__bf16)s4.x, (__bf16)s4.y, (__bf16)s4.z, (__bf16)s4.w};
    *(ushort4*)&qbf[i * 4] = *(ushort4*)ov;
}

// ---------------------------------------------------------------------------
// K4: attention via MFMA. 512 blocks (one per (c,h)); K/vp/mask staged ONCE,
// loop over 7 q-block positions internally. NO fences.
// ---------------------------------------------------------------------------
#define KROW 72   // LDS row stride in bf16 (64 data + 8 pad)

__global__ __launch_bounds__(256)
void attn_mfma_kernel(const __bf16* __restrict__ qb, const __bf16* __restrict__ kb,
                      const float* __restrict__ vpm, const float* __restrict__ vpnull,
                      const int* __restrict__ mask, float* __restrict__ s_buf) {
    __shared__ __align__(16) __bf16 ksh[128 * KROW];
    __shared__ float vpsh[128];
    __shared__ float amsh[128];
    int ch = blockIdx.x;
    int h = ch & 7, c = ch >> 3;
    int tid = threadIdx.x;
    int lane = tid & 63, w = tid >> 6;
    int n16 = lane & 15, quad = lane >> 4;

    const __bf16* kbase = kb + (long long)(c * 128) * INNER + h * DHEAD;
    #pragma unroll
    for (int p = 0; p < 4; ++p) {
        int chunk = tid + p * 256;          // 0..1023
        int row = chunk >> 3, o = chunk & 7;
        bf16x8 v = *(const bf16x8*)(kbase + (long long)row * INNER + o * 8);
        *(bf16x8*)&ksh[row * KROW + o * 8] = v;
    }
    if (tid < 128) {
        vpsh[tid] = (tid == 0) ? vpnull[h] : vpm[(long long)(c * JLEN + tid - 1) * 8 + h];
        amsh[tid] = (tid == 0) ? 0.f : (mask[tid - 1] ? 0.f : -3.0e38f);
    }
    __syncthreads();

    bf16x8 bF[8][2];
    #pragma unroll
    for (int t = 0; t < 8; ++t)
        #pragma unroll
        for (int s = 0; s < 2; ++s)
            bF[t][s] = *(const bf16x8*)&ksh[(t * 16 + n16) * KROW + s * 32 + quad * 8];

    float vpv[8], am[8];
    #pragma unroll
    for (int t = 0; t < 8; ++t) {
        vpv[t] = vpsh[t * 16 + n16];
        am[t]  = amsh[t * 16 + n16];
    }

    const __bf16* qbase = qb + h * DHEAD;
    const f32x4 zero = {0.f, 0.f, 0.f, 0.f};

    for (int xi = 0; xi < 7; ++xi) {
        bf16x8 aF[2][2];
        int r0s[2];
        #pragma unroll
        for (int it2 = 0; it2 < 2; ++it2) {
            int tile = xi * 8 + it2 * 4 + w;   // 0..55
            r0s[it2] = tile * 16;
            const __bf16* qrow = qbase + (long long)(r0s[it2] + n16) * INNER + quad * 8;
            aF[it2][0] = *(const bf16x8*)(qrow);
            aF[it2][1] = *(const bf16x8*)(qrow + 32);
        }

        #pragma unroll
        for (int it2 = 0; it2 < 2; ++it2) {
            int r0 = r0s[it2];
            f32x4 acc[8];
            #pragma unroll
            for (int t = 0; t < 8; ++t) {
                acc[t] = __builtin_amdgcn_mfma_f32_16x16x32_bf16(aF[it2][0], bF[t][0], zero,   0, 0, 0);
                acc[t] = __builtin_amdgcn_mfma_f32_16x16x32_bf16(aF[it2][1], bF[t][1], acc[t], 0, 0, 0);
            }
            float mloc = -3.0e38f;
            #pragma unroll
            for (int t = 0; t < 8; ++t)
                #pragma unroll
                for (int r = 0; r < 4; ++r)
                    mloc = fmaxf(mloc, acc[t][r] * 0.125f + am[t]);
            #pragma unroll
            for (int o = 1; o < 16; o <<= 1) mloc = fmaxf(mloc, __shfl_xor(mloc, o, 16));
            float lr[4] = {0.f, 0.f, 0.f, 0.f}, pr[4] = {0.f, 0.f, 0.f, 0.f};
            #pragma unroll
            for (int t = 0; t < 8; ++t) {
                #pragma unroll
                for (int r = 0; r < 4; ++r) {
                    float e = __expf(acc[t][r] * 0.125f + am[t] - mloc);
                    lr[r] += e; pr[r] += e * vpv[t];
                }
            }
            #pragma unroll
            for (int o = 1; o < 16; o <<= 1) {
                #pragma unroll
                for (int r = 0; r < 4; ++r) {
                    lr[r] += __shfl_xor(lr[r], o, 16);
                    pr[r] += __shfl_xor(pr[r], o, 16);
                }
            }
            if (n16 == 0) {
                #pragma unroll
                for (int r = 0; r < 4; ++r)
                    s_buf[(long long)ch * N_SEQ + r0 + quad * 4 + r] = pr[r] / lr[r];
            }
        }
    }
}

// ---------------------------------------------------------------------------
// K5: final: pred[n,c] = softplus(e_dot[n] + sum_h s[c,h,n] + bop + bp)
// ---------------------------------------------------------------------------
__global__ void final_kernel(const float* __restrict__ s_buf,
                             const float* __restrict__ e_dot,
                             const float* __restrict__ bop,
                             const float* __restrict__ bp,
                             float* __restrict__ out) {
    int t = blockIdx.x * blockDim.x + threadIdx.x;
    if (t >= N_SEQ * NCTX) return;
    int n = t >> 6, c = t & 63;
    float s = 0.f;
    #pragma unroll
    for (int h = 0; h < HEADS; ++h) s += s_buf[((long long)(c * HEADS + h)) * N_SEQ + n];
    float x = e_dot[n] + s + *bop + *bp;
    out[t] = fmaxf(x, 0.f) + log1pf(__expf(-fabsf(x)));
}

// ---------------------------------------------------------------------------
extern "C" void kernel_launch(void* const* d_in, const int* in_sizes, int n_in,
                              void* d_out, int out_size, void* d_ws, size_t ws_size,
                              hipStream_t stream) {
    const float* emb   = (const float*)d_in[0];
    const float* ctx   = (const float*)d_in[1];
    const int*   cmask = (const int*)  d_in[2];
    const float* qg    = (const float*)d_in[3];
    const float* qb_   = (const float*)d_in[4];
    const float* kvg   = (const float*)d_in[5];
    const float* kvb   = (const float*)d_in[6];
    const float* Wq    = (const float*)d_in[7];
    const float* Wkv   = (const float*)d_in[8];
    const float* nullk = (const float*)d_in[9];
    const float* nullv = (const float*)d_in[10];
    const float* Wo    = (const float*)d_in[11];
    const float* bo    = (const float*)d_in[12];
    const float* Wp    = (const float*)d_in[13];
    const float* bp    = (const float*)d_in[14];
    float* out  = (float*)d_out;
    float* ws_f = (float*)d_ws;

    float*  EDOT   = ws_f + OFF_EDOT;
    __bf16* QBF    = (__bf16*)(ws_f + OFF_QBF);
    __bf16* KBF    = (__bf16*)(ws_f + OFF_KBF);
    float*  VPM    = ws_f + OFF_VPM;
    float*  VPNULL = ws_f + OFF_VPNULL;
    float*  BOP    = ws_f + OFF_BOP;
    float*  SBUF   = ws_f + OFF_SBUF;
    __bf16* ANQ    = (__bf16*)(ws_f + OFF_ANQ);
    __bf16* ANKV   = (__bf16*)(ws_f + OFF_ANKV);
    __bf16* WQT    = (__bf16*)(ws_f + OFF_WQT);
    __bf16* WKT    = (__bf16*)(ws_f + OFF_WKT);
    __bf16* WVPT   = (__bf16*)(ws_f + OFF_WVPT);
    float*  QSL    = ws_f + OFF_QSL;

    prep_kernel<<<GRIDP, 256, 0, stream>>>(
        emb, ctx, qg, qb_, kvg, kvb, Wq, Wkv, Wo, bo, Wp, nullk, nullv,
        ANQ, ANKV, WQT, WKT, WVPT, VPNULL, EDOT, BOP, KBF);
    proj_kernel<<<480, 256, 0, stream>>>(ANQ, WQT, ANKV, WKT, WVPT, QSL, KBF, VPM);
    qreduce_kernel<<<(N_SEQ * INNER) / 1024, 256, 0, stream>>>(QSL, QBF);
    attn_mfma_kernel<<<NCTX * HEADS, 256, 0, stream>>>(
        QBF, KBF, VPM, VPNULL, cmask, SBUF);
    final_kernel<<<(N_SEQ * NCTX + 255) / 256, 256, 0, stream>>>(SBUF, EDOT, BOP, bp, out);
}